// Round 3
// baseline (684.446 us; speedup 1.0000x reference)
//
#include <hip/hip_runtime.h>
#include <hip/hip_bf16.h>
#include <cstdint>
#include <math.h>

#define BATCH    65536
#define HIS_LEN  5
#define KIND_LEN 10

// ---- ws layout (fp32 element offsets) ----
#define OFF_WC1 0        // [64][176]  (wA+wB | wC-wB)
#define OFF_AB1 11264    // [64]
#define OFF_W2T 11328    // [64][32]   act_w2 transposed -> w2t[o*32+p]
#define OFF_AB2 13376    // [32]
#define OFF_W3  13408    // [32]
#define OFF_AB3 13440    // [1] (padded 16)
#define OFF_M1  13456    // [128][208]
#define OFF_MB1 40080    // [128]
#define OFF_M2T 40208    // [128][64]  mlp_w2 transposed -> m2t[o*64+p]
#define OFF_MB2 48400    // [64]
#define OFF_M3T 48464    // [64][32]   mlp_w3 transposed -> m3t[o*32+p]
#define OFF_MB3 50512    // [32]
#define OFF_M4  50544    // [32]
#define OFF_MB4 50576    // [1]
#define PREP_N  50562

// load one 8-float embedding row (32 bytes) via two float4 loads
__device__ __forceinline__ void load8(const float4* __restrict__ e, int idx, float* d){
  float4 a = e[idx*2];
  float4 b = e[idx*2+1];
  d[0]=a.x; d[1]=a.y; d[2]=a.z; d[3]=a.w;
  d[4]=b.x; d[5]=b.y; d[6]=b.z; d[7]=b.w;
}

// build one 88-float item feature: [item_emb row (8) | 10 masked kind rows (80)]
__device__ __forceinline__ void gather_item_feat(const float4* __restrict__ item_emb,
                                                 const float4* __restrict__ kind_emb,
                                                 int item_idx,
                                                 const int* __restrict__ kidx,
                                                 float* f){
  load8(item_emb, item_idx, f);
  #pragma unroll
  for(int k=0;k<KIND_LEN;k++){
    int ki = kidx[k];
    float t[8]; load8(kind_emb, ki, t);
    #pragma unroll
    for(int j=0;j<8;j++) f[8+8*k+j] = ki ? t[j] : 0.0f;
  }
}

typedef const float* fp;

// ---- prep: combine/transpose all weights (fp32) into ws ----
__global__ void din_prep(fp aw1, fp ab1, fp aw2, fp ab2, fp aw3, fp ab3,
                         fp m1,  fp mb1, fp m2,  fp mb2, fp m3,  fp mb3,
                         fp m4,  fp mb4, float* __restrict__ ws){
  int i = blockIdx.x*blockDim.x + threadIdx.x;
  int j = i;
  if(j < 11264){ // combined act_w1: row o, 176 wide
    int o = j/176, d = j%176;
    float v;
    if(d < 88) v = aw1[o*264 + d] + aw1[o*264 + 88 + d];
    else { int dd = d-88; v = aw1[o*264 + 176 + dd] - aw1[o*264 + 88 + dd]; }
    ws[OFF_WC1 + j] = v; return;
  } j -= 11264;
  if(j < 64){ ws[OFF_AB1 + j] = ab1[j]; return; } j -= 64;
  if(j < 2048){ int o=j/32, p=j%32; ws[OFF_W2T + j] = aw2[p*64 + o]; return; } j -= 2048;
  if(j < 32){ ws[OFF_AB2 + j] = ab2[j]; return; } j -= 32;
  if(j < 32){ ws[OFF_W3  + j] = aw3[j]; return; } j -= 32;
  if(j < 1){ ws[OFF_AB3] = ab3[0]; return; } j -= 1;
  if(j < 26624){ ws[OFF_M1 + j] = m1[j]; return; } j -= 26624;
  if(j < 128){ ws[OFF_MB1 + j] = mb1[j]; return; } j -= 128;
  if(j < 8192){ int o=j/64, p=j%64; ws[OFF_M2T + j] = m2[p*128 + o]; return; } j -= 8192;
  if(j < 64){ ws[OFF_MB2 + j] = mb2[j]; return; } j -= 64;
  if(j < 2048){ int o=j/32, p=j%32; ws[OFF_M3T + j] = m3[p*64 + o]; return; } j -= 2048;
  if(j < 32){ ws[OFF_MB3 + j] = mb3[j]; return; } j -= 32;
  if(j < 32){ ws[OFF_M4  + j] = m4[j];  return; } j -= 32;
  if(j < 1){ ws[OFF_MB4] = mb4[0]; return; }
}

// accumulate val into one of 4 rotating accumulators (compile-time t)
#define ACC4(t, val) do{ int _q=(t)&3; float _v=(val); \
  if(_q==0) a0+=_v; else if(_q==1) a1+=_v; else if(_q==2) a2+=_v; else a3+=_v; }while(0)

__global__ void __launch_bounds__(64, 1)
din_main(const int* __restrict__ userid, const int* __restrict__ itemid,
         const int* __restrict__ age,    const int* __restrict__ gen,
         const int* __restrict__ occ,    const int* __restrict__ item_kind,
         const int* __restrict__ his_id, const int* __restrict__ his_kind,
         const float4* __restrict__ user_emb, const float4* __restrict__ item_emb,
         const float4* __restrict__ age_emb,  const float4* __restrict__ gen_emb,
         const float4* __restrict__ occ_emb,  const float4* __restrict__ kind_emb,
         const float* __restrict__ ws, float* __restrict__ out){
  const int lane = threadIdx.x;
  const int b = blockIdx.x*64 + lane;

  __shared__ float t2s[64*64];   // [o][lane]; per-lane private column, same-wave, no sync

  // ---- current-item feature i2 (88) ----
  float i2[88];
  gather_item_feat(item_emb, kind_emb, itemid[b], item_kind + b*KIND_LEN, i2);

  // ---- t2[o] = dot(wC-wB, i2), position-invariant ----
  #pragma unroll 1
  for(int o=0;o<64;o++){
    const float* __restrict__ w = ws + OFF_WC1 + o*176 + 88;
    float a0=0.f,a1=0.f,a2=0.f,a3=0.f;
    #pragma unroll
    for(int d=0;d<88;d+=4){ a0+=w[d]*i2[d]; a1+=w[d+1]*i2[d+1]; a2+=w[d+2]*i2[d+2]; a3+=w[d+3]*i2[d+3]; }
    t2s[o*64 + lane] = (a0+a1)+(a2+a3);
  }

  float pool[88];
  #pragma unroll
  for(int d=0;d<88;d++) pool[d]=0.f;

  // ---- history positions ----
  #pragma unroll 1
  for(int s=0;s<HIS_LEN;s++){
    float i1[88];
    gather_item_feat(item_emb, kind_emb, his_id[b*HIS_LEN+s], his_kind + (b*HIS_LEN+s)*KIND_LEN, i1);

    float h2[32];
    #pragma unroll
    for(int p=0;p<32;p++) h2[p] = ws[OFF_AB2+p];

    #pragma unroll 1
    for(int o=0;o<64;o++){
      const float* __restrict__ w = ws + OFF_WC1 + o*176;
      float a0=0.f,a1=0.f,a2=0.f,a3=0.f;
      #pragma unroll
      for(int d=0;d<88;d+=4){ a0+=w[d]*i1[d]; a1+=w[d+1]*i1[d+1]; a2+=w[d+2]*i1[d+2]; a3+=w[d+3]*i1[d+3]; }
      float h = (a0+a1)+(a2+a3) + t2s[o*64+lane] + ws[OFF_AB1+o];
      h = fmaxf(h, 0.f);
      const float* __restrict__ w2 = ws + OFF_W2T + o*32;
      #pragma unroll
      for(int p=0;p<32;p++) h2[p] += w2[p]*h;
    }
    float sc = ws[OFF_AB3];
    #pragma unroll
    for(int p=0;p<32;p++) sc += ws[OFF_W3+p]*fmaxf(h2[p],0.f);
    // pool += score * i1^2
    #pragma unroll
    for(int d=0;d<88;d++){ float t = sc*i1[d]; pool[d] += t*i1[d]; }
  }

  // ---- main MLP ----
  float uf[8], af[8], gf[8], qf[8];
  load8(user_emb, userid[b], uf);
  load8(age_emb, age[b], af);
  load8(gen_emb, gen[b], gf);
  load8(occ_emb, occ[b], qf);

  float h2m[64];
  #pragma unroll
  for(int p=0;p<64;p++) h2m[p] = ws[OFF_MB2+p];

  #pragma unroll 1
  for(int o=0;o<128;o++){
    const float* __restrict__ w = ws + OFF_M1 + o*208;
    float a0=0.f,a1=0.f,a2=0.f,a3=0.f;
    // all_feat = [user(0:8) item(8:16) age(16:24) gen(24:32) occ(32:40) kind(40:120) pool(120:208)]
    #pragma unroll
    for(int j=0;j<8;j++)  ACC4(j,      w[j]      * uf[j]);
    #pragma unroll
    for(int j=0;j<8;j++)  ACC4(8+j,    w[8+j]    * i2[j]);
    #pragma unroll
    for(int j=0;j<8;j++)  ACC4(16+j,   w[16+j]   * af[j]);
    #pragma unroll
    for(int j=0;j<8;j++)  ACC4(24+j,   w[24+j]   * gf[j]);
    #pragma unroll
    for(int j=0;j<8;j++)  ACC4(32+j,   w[32+j]   * qf[j]);
    #pragma unroll
    for(int j=0;j<80;j++) ACC4(40+j,   w[40+j]   * i2[8+j]);
    #pragma unroll
    for(int j=0;j<88;j++) ACC4(120+j,  w[120+j]  * pool[j]);
    float h = fmaxf((a0+a1)+(a2+a3) + ws[OFF_MB1+o], 0.f);
    const float* __restrict__ w2 = ws + OFF_M2T + o*64;
    #pragma unroll
    for(int p=0;p<64;p++) h2m[p] += w2[p]*h;
  }

  float h3[32];
  #pragma unroll
  for(int p=0;p<32;p++) h3[p] = ws[OFF_MB3+p];
  #pragma unroll
  for(int o=0;o<64;o++){
    float v = fmaxf(h2m[o],0.f);
    const float* __restrict__ w3 = ws + OFF_M3T + o*32;
    #pragma unroll
    for(int p=0;p<32;p++) h3[p] += w3[p]*v;
  }
  float x = ws[OFF_MB4];
  #pragma unroll
  for(int o=0;o<32;o++) x += ws[OFF_M4+o]*fmaxf(h3[o],0.f);

  float sg = 1.0f/(1.0f + __expf(-x));
  out[b] = sg;
}

extern "C" void kernel_launch(void* const* d_in, const int* in_sizes, int n_in,
                              void* d_out, int out_size, void* d_ws, size_t ws_size,
                              hipStream_t stream){
  // inputs in setup_inputs() order
  const int* userid    = (const int*)d_in[0];
  const int* itemid    = (const int*)d_in[1];
  const int* age       = (const int*)d_in[2];
  const int* gen       = (const int*)d_in[3];
  const int* occ       = (const int*)d_in[4];
  const int* item_kind = (const int*)d_in[5];
  const int* his_id    = (const int*)d_in[6];
  const int* his_kind  = (const int*)d_in[7];
  const float4* user_emb = (const float4*)d_in[8];
  const float4* item_emb = (const float4*)d_in[9];
  const float4* age_emb  = (const float4*)d_in[10];
  const float4* gen_emb  = (const float4*)d_in[11];
  const float4* occ_emb  = (const float4*)d_in[12];
  const float4* kind_emb = (const float4*)d_in[13];
  float* ws = (float*)d_ws;

  din_prep<<<(PREP_N+255)/256, 256, 0, stream>>>(
      (fp)d_in[14], (fp)d_in[15], (fp)d_in[16], (fp)d_in[17], (fp)d_in[18], (fp)d_in[19],
      (fp)d_in[20], (fp)d_in[21], (fp)d_in[22], (fp)d_in[23], (fp)d_in[24], (fp)d_in[25],
      (fp)d_in[26], (fp)d_in[27], ws);

  din_main<<<BATCH/64, 64, 0, stream>>>(
      userid, itemid, age, gen, occ, item_kind, his_id, his_kind,
      user_emb, item_emb, age_emb, gen_emb, occ_emb, kind_emb,
      ws, (float*)d_out);
}